// Round 2
// baseline (75.625 us; speedup 1.0000x reference)
//
#include <hip/hip_runtime.h>
#include <stdint.h>

// y[m][n] = scales[n] * sum_k x[m][k]*W[n][k] + bias[n]
// M=128, K=4096, N=11008. x fp32; W int8 VALUES delivered as int32 on device
// (harness: "integer -> const int*"); scales/bias fp32; out fp32.
//
// Memory-bound regime: weights are 180 MB int32 -> HBM floor ~28.6us.
// Structure:
//   pack_x: x fp32 -> bf16 in MFMA A-frag order into ws (1 MiB). GEMM then
//           stages A with global_load_lds(16B); all ds_read_b128 lane-linear.
//   gemm:   full-K blocks, BM=128 x BN=32, BK=64, 4 waves, 40KB LDS
//           -> 4 blocks/CU, all 344 blocks co-resident (self-balancing).
//           W staged int32->regs, v_cvt_f32_i32 (exact) -> bf16 truncate
//           (exact, |w|<=128) -> LDS B-frags. Epilogue fused (scales,bias).

#define M_ROWS 128
#define K_DIM  4096
#define N_DIM  11008
#define BN     32
#define BK     64
#define NTILES (N_DIM / BN)   // 344
#define CHUNKS (K_DIM / BK)   // 64

#define XP_BYTES (M_ROWS * K_DIM * 2)  // 1 MiB packed bf16 x

typedef __attribute__((ext_vector_type(8))) short bf16x8;
typedef __attribute__((ext_vector_type(4))) float f32x4;
typedef const unsigned __attribute__((address_space(1)))* gas1_t;
typedef unsigned __attribute__((address_space(3)))* las3_t;

__device__ __forceinline__ unsigned bf16_rn(float f) {
  unsigned u = __float_as_uint(f);
  return (u + 0x7FFFu + ((u >> 16) & 1u)) >> 16;   // round-to-nearest-even
}

__device__ __forceinline__ void gload_lds16(const void* g, void* lds) {
#if __has_builtin(__builtin_amdgcn_global_load_lds)
  // generic LDS pointer low 32 bits == LDS byte offset (aperture-high layout)
  __builtin_amdgcn_global_load_lds((gas1_t)g, (las3_t)(size_t)(unsigned)(size_t)lds,
                                   16, 0, 0);
#else
  *(uint4*)lds = *(const uint4*)g;  // synchronous fallback (correct)
#endif
}

// ---------------- pack x: fp32 -> bf16 in A-frag order ----------------
// Chunk kk (64 k) = 16 KiB contiguous: unit u = (mf*2 + s)*64 + lane (16B each)
// frag (mf,s): lane l holds x[16*mf + (l&15)][kk*64 + s*32 + 8*(l>>4) + j]
__global__ __launch_bounds__(256) void pack_x_kernel(
    const float* __restrict__ x, unsigned short* __restrict__ xp) {
  int tid  = blockIdx.x * 256 + threadIdx.x;   // 65536 threads
  int lane = tid & 63;
  int h    = (tid >> 6) & 1;
  int mf   = (tid >> 7) & 7;
  int kk   = tid >> 10;
  int m     = mf * 16 + (lane & 15);
  int kbase = kk * 64 + h * 32 + ((lane >> 4) * 8);
  const float* src = x + (size_t)m * K_DIM + kbase;
  float4 f0 = *(const float4*)(src);
  float4 f1 = *(const float4*)(src + 4);
  float v[8] = {f0.x, f0.y, f0.z, f0.w, f1.x, f1.y, f1.z, f1.w};
  unsigned po[4];
#pragma unroll
  for (int i = 0; i < 4; ++i)
    po[i] = bf16_rn(v[2 * i]) | (bf16_rn(v[2 * i + 1]) << 16);
  *(uint4*)(xp + (size_t)tid * 8) = *(uint4*)po;
}

// ---------------- main GEMM (full K per block) ----------------
__global__ __launch_bounds__(256, 4) void w8a16_gemm_kernel(
    const unsigned short* __restrict__ xp,
    const int* __restrict__ wq,
    const float* __restrict__ scales,
    const float* __restrict__ bias,
    float* __restrict__ out) {
  __shared__ char smem[2 * 16384 + 2 * 4096];  // A dbuf 16K each @0; B dbuf 4K each @32768

  const int tid  = threadIdx.x;
  const int lane = tid & 63;
  const int w    = tid >> 6;           // wave 0..3 -> rows [32w, 32w+32)
  const size_t n0 = (size_t)blockIdx.x * BN;

  // ---- B staging geometry: thread covers W[n0+n][k: q*4..+4) per 32-k half
  const int bn_ = tid >> 3;            // n within tile, 0..31
  const int bq  = tid & 7;             // 16B group along k
  const int* bsrc = wq + (n0 + (size_t)bn_) * K_DIM + bq * 4;
  // dst byte offset inside a B buffer for half g: +g*1024
  const int bOff = (bn_ >> 4) * 2048 + (bq >> 1) * 256 + (bn_ & 15) * 16 + (bq & 1) * 8;

  // ---- A staging geometry: wave w stages bytes [w*4096, +4096) of each 16K chunk
  const int aoff = w * 4096 + lane * 16;
  const char* asrc = (const char*)xp + aoff;

  f32x4 acc[2][2];
  {
    f32x4 z = {0.f, 0.f, 0.f, 0.f};
#pragma unroll
    for (int i = 0; i < 2; ++i)
#pragma unroll
      for (int j = 0; j < 2; ++j) acc[i][j] = z;
  }

  auto stageA = [&](int t, int abase) {
#pragma unroll
    for (int i = 0; i < 4; ++i)
      gload_lds16(asrc + (size_t)t * 16384 + i * 1024, smem + abase + aoff + i * 1024);
  };
  auto cvt2 = [](int a, int b) -> unsigned {
    // two exact int->f32->bf16, packed
    return (__float_as_uint((float)b) & 0xFFFF0000u) | (__float_as_uint((float)a) >> 16);
  };
  auto writeB = [&](uint4 v, int g, int bbase) {
    uint2 val;
    val.x = cvt2((int)v.x, (int)v.y);
    val.y = cvt2((int)v.z, (int)v.w);
    *(uint2*)(smem + bbase + bOff + g * 1024) = val;
  };

  // prologue: chunk 0 -> buffers 0
  {
    uint4 b0 = *(const uint4*)(bsrc);
    uint4 b1 = *(const uint4*)(bsrc + 32);
    stageA(0, 0);
    writeB(b0, 0, 32768);
    writeB(b1, 1, 32768);
  }
  __syncthreads();

  int cur = 0;
#pragma unroll 1
  for (int t = 0; t < CHUNKS; ++t) {
    const int nxt = cur ^ 1;
    const int aCur = cur * 16384, bCur = 32768 + cur * 4096;
    uint4 bA, bB;
    if (t + 1 < CHUNKS) {
      bA = *(const uint4*)(bsrc + (t + 1) * 64);        // next B -> regs
      bB = *(const uint4*)(bsrc + (t + 1) * 64 + 32);
      stageA(t + 1, nxt * 16384);                       // next A -> LDS (async)
    }
    // compute chunk t: 2 K32 steps x (2 M-frags x 2 N-frags)
#pragma unroll
    for (int s = 0; s < 2; ++s) {
      bf16x8 a0 = *(const bf16x8*)(smem + aCur + aoff + s * 1024);
      bf16x8 a1 = *(const bf16x8*)(smem + aCur + aoff + 2048 + s * 1024);
      bf16x8 b0 = *(const bf16x8*)(smem + bCur + lane * 16 + s * 1024);
      bf16x8 b1 = *(const bf16x8*)(smem + bCur + lane * 16 + 2048 + s * 1024);
      acc[0][0] = __builtin_amdgcn_mfma_f32_16x16x32_bf16(a0, b0, acc[0][0], 0, 0, 0);
      acc[0][1] = __builtin_amdgcn_mfma_f32_16x16x32_bf16(a0, b1, acc[0][1], 0, 0, 0);
      acc[1][0] = __builtin_amdgcn_mfma_f32_16x16x32_bf16(a1, b0, acc[1][0], 0, 0, 0);
      acc[1][1] = __builtin_amdgcn_mfma_f32_16x16x32_bf16(a1, b1, acc[1][1], 0, 0, 0);
    }
    if (t + 1 < CHUNKS) {                               // convert+store next B
      writeB(bA, 0, 32768 + nxt * 4096);
      writeB(bB, 1, 32768 + nxt * 4096);
    }
    __syncthreads();   // drains vmcnt (A nxt resident) + lgkmcnt (B nxt written)
    cur = nxt;
  }

  // ---- fused epilogue: out = scales*acc + bias
  // C/D frag: n = n0 + j*16 + (lane&15); m = w*32 + i*16 + (lane>>4)*4 + r
#pragma unroll
  for (int j = 0; j < 2; ++j) {
    const size_t n = n0 + (size_t)(j * 16 + (lane & 15));
    const float sc = scales[n];
    const float bi = bias[n];
#pragma unroll
    for (int i = 0; i < 2; ++i) {
      const int mb = w * 32 + i * 16 + (lane >> 4) * 4;
#pragma unroll
      for (int r = 0; r < 4; ++r)
        out[(size_t)(mb + r) * N_DIM + n] = sc * acc[i][j][r] + bi;
    }
  }
}

// ---------------- insurance path if ws is too small ----------------
__global__ __launch_bounds__(256) void naive_kernel(
    const float* __restrict__ x, const int* __restrict__ wq,
    const float* __restrict__ scales, const float* __restrict__ bias,
    float* __restrict__ out) {
  const int n = blockIdx.x * 256 + threadIdx.x;
  const int m = blockIdx.y;
  const float* xr = x + (size_t)m * K_DIM;
  const int* wr = wq + (size_t)n * K_DIM;
  float s = 0.f;
  for (int k = 0; k < K_DIM; k += 4) {
    float4 xv = *(const float4*)(xr + k);
    int4  wv = *(const int4*)(wr + k);
    s += xv.x * (float)wv.x + xv.y * (float)wv.y +
         xv.z * (float)wv.z + xv.w * (float)wv.w;
  }
  out[(size_t)m * N_DIM + n] = scales[n] * s + bias[n];
}

extern "C" void kernel_launch(void* const* d_in, const int* in_sizes, int n_in,
                              void* d_out, int out_size, void* d_ws, size_t ws_size,
                              hipStream_t stream) {
  const float* x        = (const float*)d_in[0];
  const int* wq         = (const int*)d_in[1];
  const float* scales   = (const float*)d_in[2];
  const float* bias     = (const float*)d_in[3];
  float* out            = (float*)d_out;

  if (ws_size < (size_t)XP_BYTES) {
    naive_kernel<<<dim3(N_DIM / 256, M_ROWS), 256, 0, stream>>>(x, wq, scales, bias, out);
    return;
  }
  unsigned short* xp = (unsigned short*)d_ws;
  pack_x_kernel<<<256, 256, 0, stream>>>(x, xp);
  w8a16_gemm_kernel<<<dim3(NTILES), 256, 0, stream>>>(xp, wq, scales, bias, out);
}